// Round 12
// baseline (161.577 us; speedup 1.0000x reference)
//
#include <hip/hip_runtime.h>

// BatchWiseSimCLR: out = mean_b,i logsumexp_{j!=i}(cos(z_bi,z_bj)/T) - mean_r cos(x_r,xp_r)/T
// 2B=128 batch rows, MS=512 items/batch, D=256, T=0.5.

#define TWO_B   128
#define MS      512
#define DDIM    256
#define NROWS   32768          // TWO_B * K = 128*256
#define TEMP_INV 2.0f
#define EPSN     1e-8f
#define SQRT2   1.41421356237f

typedef __attribute__((ext_vector_type(8))) short  short8;   // 8 x bf16 (4 VGPRs)
typedef __attribute__((ext_vector_type(4))) float  f32x4;    // MFMA acc

__device__ __forceinline__ unsigned short f2bf(float f) {
  union { float f; unsigned u; } c; c.f = f;
  unsigned r = (c.u + 0x7FFFu + ((c.u >> 16) & 1u)) >> 16;   // RNE
  return (unsigned short)r;
}

// ================= FAST PATH (needs 32MB+4KB workspace) =================
// zn2 layout (MFMA-native tiles, NO swizzle): per b, 32 tiles of 16 rows;
// ushort offset = b*131072 + (j>>4)*4096 + (j&15)*256 + col.
// Rows are 512B contiguous -> k_norm writes coalesced; an MFMA fragment load
// (row l15, 16B at col kk*32+hi*8) is one global dwordx4 (16 x 64B segments).

// ---- K1f: row norms + write normalized bf16 zn2 (scaled by sqrt2) ----
__global__ __launch_bounds__(256) void k_norm_f(
    const float* __restrict__ x, const float* __restrict__ xp,
    unsigned short* __restrict__ zn2) {
  const int wid = threadIdx.x >> 6, lane = threadIdx.x & 63;
  #pragma unroll
  for (int itr = 0; itr < 4; ++itr) {
    const int r = itr * 8192 + blockIdx.x * 4 + wid;
    const int b = r & 127, i = r >> 7;          // r = i*128 + b
    const float4 a = ((const float4*)(x  + (size_t)r * DDIM))[lane];
    const float4 p = ((const float4*)(xp + (size_t)r * DDIM))[lane];
    float sxx = a.x*a.x + a.y*a.y + a.z*a.z + a.w*a.w;
    float spp = p.x*p.x + p.y*p.y + p.z*p.z + p.w*p.w;
    #pragma unroll
    for (int m = 1; m < 64; m <<= 1) {
      sxx += __shfl_xor(sxx, m);
      spp += __shfl_xor(spp, m);
    }
    const float inx = SQRT2 / fmaxf(sqrtf(sxx), EPSN);
    const float inp = SQRT2 / fmaxf(sqrtf(spp), EPSN);
    ushort4 ox, op;
    ox.x = f2bf(a.x * inx); ox.y = f2bf(a.y * inx);
    ox.z = f2bf(a.z * inx); ox.w = f2bf(a.w * inx);
    op.x = f2bf(p.x * inp); op.y = f2bf(p.y * inp);
    op.z = f2bf(p.z * inp); op.w = f2bf(p.w * inp);
    const int jx = i, jp = 256 + i;             // two destination rows
    const size_t base = (size_t)b * 131072;
    *(ushort4*)(zn2 + base + (jx >> 4) * 4096 + (jx & 15) * 256 + lane * 4) = ox;
    *(ushort4*)(zn2 + base + (jp >> 4) * 4096 + (jp & 15) * 256 + lane * 4) = op;
  }
}

// ---- K2f: gram + exp row-sums, ZERO LDS / ZERO staging ----
// Grid (b=128, it=4). 4 waves/block; wave owns 32 A-rows (av[2][8] regs).
// B read straight from zn2 (L1/L2): 32 tiles of 16 rows, 2-deep bv pipeline.
// Bare s_barrier every 2 tiles keeps the 4 waves aligned for L1 reuse.
__global__ __launch_bounds__(256, 3) void k_neg_f5(
    const unsigned short* __restrict__ zn2,
    float* __restrict__ negp, float* __restrict__ posn) {
  const int b  = blockIdx.x;      // same-b blocks -> same XCD (ids differ by 128)
  const int it = blockIdx.y;      // 0..3, 128-row A tile
  const int lane = threadIdx.x & 63, wid = threadIdx.x >> 6;
  const int l15 = lane & 15, hi = lane >> 4;
  const int ri = hi << 2;                        // C/D row base within 16-tile
  const unsigned short* zb = zn2 + (size_t)b * 131072;
  const int fr = l15 * 256 + hi * 8;             // frag offset within a tile

  // A-frags: wave owns rows it*128 + wid*32 .. +31  (tiles it*8+wid*2 {+0,+1})
  short8 av[2][8];
  #pragma unroll
  for (int rb = 0; rb < 2; ++rb) {
    const unsigned short* gt = zb + (it * 8 + wid * 2 + rb) * 4096 + fr;
    #pragma unroll
    for (int kk = 0; kk < 8; ++kk)
      av[rb][kk] = *(const short8*)(gt + kk * 32);
  }

  float rowacc[2][4] = {{0,0,0,0},{0,0,0,0}};
  float posl = 0.0f;
  const int tb0 = it * 128 + wid * 32;           // wave's first global A-row

  #define LOADB(BV, BT)                                                        \
    {                                                                          \
      const unsigned short* gt = zb + (BT) * 4096 + fr;                        \
      _Pragma("unroll")                                                        \
      for (int kk = 0; kk < 8; ++kk) (BV)[kk] = *(const short8*)(gt + kk * 32);\
    }

  // one 16-col B tile: 16 MFMA + epilogue (exp + diag/pos, wave-uniform tests)
  #define TILE_STEP(BV, BT)                                                    \
    {                                                                          \
      f32x4 a0 = {0, 0, 0, 0}, a1 = {0, 0, 0, 0};                              \
      _Pragma("unroll")                                                        \
      for (int kk = 0; kk < 8; ++kk) {                                         \
        a0 = __builtin_amdgcn_mfma_f32_16x16x32_bf16(av[0][kk], (BV)[kk], a0, 0, 0, 0); \
        a1 = __builtin_amdgcn_mfma_f32_16x16x32_bf16(av[1][kk], (BV)[kk], a1, 0, 0, 0); \
      }                                                                        \
      const int jtb = (BT) * 16;                                               \
      _Pragma("unroll")                                                        \
      for (int rb = 0; rb < 2; ++rb) {                                         \
        const int tb = tb0 + rb * 16;                                          \
        const bool dtile = (jtb == tb);         /* wave-uniform */             \
        const bool ptile = (jtb == tb + 256);   /* wave-uniform */             \
        _Pragma("unroll")                                                      \
        for (int r2 = 0; r2 < 4; ++r2) {                                       \
          const float s = rb ? a1[r2] : a0[r2]; /* = cos/T (sqrt2 fold) */     \
          float e = __expf(s);                                                 \
          if (dtile && l15 == ri + r2) e = 0.0f;                               \
          rowacc[rb][r2] += e;                                                 \
          if (ptile && l15 == ri + r2) posl += s;                              \
        }                                                                      \
      }                                                                        \
    }

  short8 bva[8], bvb[8];
  LOADB(bva, 0);
  for (int bt = 0; bt < 32; bt += 2) {
    LOADB(bvb, bt + 1);
    TILE_STEP(bva, bt);
    if (bt + 2 < 32) LOADB(bva, bt + 2);
    TILE_STEP(bvb, bt + 1);
    __builtin_amdgcn_s_barrier();               // align waves for L1 reuse
  }
  #undef LOADB
  #undef TILE_STEP

  // full row sums within each 16-lane group (block covers all 512 cols),
  // then one log per row; xor16/32 combines one representative per group.
  float partial = 0.0f;
  #pragma unroll
  for (int rb = 0; rb < 2; ++rb)
    #pragma unroll
    for (int r2 = 0; r2 < 4; ++r2) {
      float v = rowacc[rb][r2];
      v += __shfl_xor(v, 1); v += __shfl_xor(v, 2);
      v += __shfl_xor(v, 4); v += __shfl_xor(v, 8);
      partial += __logf(v);
    }
  partial += __shfl_xor(partial, 16);
  partial += __shfl_xor(partial, 32);
  // posl: distinct contributions per lane -> full butterfly
  #pragma unroll
  for (int m = 1; m < 64; m <<= 1) posl += __shfl_xor(posl, m);

  __shared__ float sn[4], sp2[4];
  if (lane == 0) { sn[wid] = partial; sp2[wid] = posl; }
  __syncthreads();
  if (threadIdx.x == 0) {
    const int bid = blockIdx.y * TWO_B + blockIdx.x;
    negp[bid] = sn[0] + sn[1] + sn[2] + sn[3];
    posn[bid] = sp2[0] + sp2[1] + sp2[2] + sp2[3];
  }
}

// ---- K3f: reduce the two 512-entry partial arrays ----
__global__ __launch_bounds__(256) void k_fin_f(
    const float* __restrict__ posn, const float* __restrict__ negp,
    float* __restrict__ out) {
  const int t = threadIdx.x, wid = t >> 6, lane = t & 63;
  float p = posn[t] + posn[t + 256];
  float n = negp[t] + negp[t + 256];
  #pragma unroll
  for (int m = 1; m < 64; m <<= 1) { p += __shfl_xor(p, m); n += __shfl_xor(n, m); }
  __shared__ float sp[4], sq[4];
  if (lane == 0) { sp[wid] = p; sq[wid] = n; }
  __syncthreads();
  if (t == 0) {
    const float pt = sp[0] + sp[1] + sp[2] + sp[3];
    const float nt = sq[0] + sq[1] + sq[2] + sq[3];
    out[0] = nt * (1.0f / 65536.0f) - pt * (1.0f / 32768.0f);
  }
}

// ================= FALLBACK PATH (R5, small workspace, verified) =================

__global__ __launch_bounds__(256) void k_norm(
    const float* __restrict__ x, const float* __restrict__ xp,
    float* __restrict__ invx, float* __restrict__ invp, float* __restrict__ posp) {
  const int wid = threadIdx.x >> 6, lane = threadIdx.x & 63;
  float posl = 0.0f;
  #pragma unroll
  for (int itr = 0; itr < 8; ++itr) {
    const int r = itr * 4096 + blockIdx.x * 4 + wid;
    const float4 a = ((const float4*)(x  + (size_t)r * DDIM))[lane];
    const float4 b = ((const float4*)(xp + (size_t)r * DDIM))[lane];
    float sxx = a.x*a.x + a.y*a.y + a.z*a.z + a.w*a.w;
    float spp = b.x*b.x + b.y*b.y + b.z*b.z + b.w*b.w;
    float sxp = a.x*b.x + a.y*b.y + a.z*b.z + a.w*b.w;
    #pragma unroll
    for (int m = 1; m < 64; m <<= 1) {
      sxx += __shfl_xor(sxx, m);
      spp += __shfl_xor(spp, m);
      sxp += __shfl_xor(sxp, m);
    }
    const float inx = 1.0f / fmaxf(sqrtf(sxx), EPSN);
    const float inp = 1.0f / fmaxf(sqrtf(spp), EPSN);
    if (lane == 0) {
      invx[r] = inx; invp[r] = inp;
      posl += sxp * inx * inp * TEMP_INV;
    }
  }
  __shared__ float cp[4];
  if (lane == 0) cp[wid] = posl;
  __syncthreads();
  if (threadIdx.x == 0) posp[blockIdx.x] = cp[0] + cp[1] + cp[2] + cp[3];
}

__device__ __forceinline__ void stage_tile(
    unsigned short* dst, const float* __restrict__ x, const float* __restrict__ xp,
    const float* __restrict__ invx, const float* __restrict__ invp, int b, int tilebase) {
  const int t = threadIdx.x;
  const bool isp = (tilebase >= 256);
  const float* src = isp ? xp : x;
  const float* inv = isp ? invp : invx;
  const int base_i = isp ? (tilebase - 256) : tilebase;
  #pragma unroll
  for (int s = 0; s < 16; ++s) {
    const int u   = s * 256 + t;
    const int row = u >> 6, c4 = u & 63;
    const int g   = (base_i + row) * TWO_B + b;
    const float4 v = *(const float4*)(src + (size_t)g * DDIM + c4 * 4);
    const float sc = inv[g];
    ushort4 o;
    o.x = f2bf(v.x * sc); o.y = f2bf(v.y * sc);
    o.z = f2bf(v.z * sc); o.w = f2bf(v.w * sc);
    *(ushort4*)(dst + row * 256 + ((c4 * 4) ^ ((row & 7) << 3))) = o;
  }
}

__global__ __launch_bounds__(256, 2) void k_neg(
    const float* __restrict__ x, const float* __restrict__ xp,
    const float* __restrict__ invx, const float* __restrict__ invp,
    float* __restrict__ negp) {
  __shared__ __align__(16) unsigned short As[64 * 256];
  __shared__ __align__(16) unsigned short Bs[64 * 256];
  const int b  = blockIdx.x;
  const int it = blockIdx.y;
  const int lane = threadIdx.x & 63, wid = threadIdx.x >> 6;

  stage_tile(As, x, xp, invx, invp, b, it * 64);
  float rowacc[4] = {0, 0, 0, 0};

  for (int jt = 0; jt < 8; ++jt) {
    __syncthreads();
    stage_tile(Bs, x, xp, invx, invp, b, jt * 64);
    __syncthreads();

    f32x4 acc[4] = {{0,0,0,0},{0,0,0,0},{0,0,0,0},{0,0,0,0}};
    #pragma unroll
    for (int kk = 0; kk < 8; ++kk) {
      const int col = kk * 32 + ((lane >> 4) << 3);
      const int ar  = wid * 16 + (lane & 15);
      const short8 av = *(const short8*)(As + ar * 256 + (col ^ ((ar & 7) << 3)));
      #pragma unroll
      for (int ni = 0; ni < 4; ++ni) {
        const int br = ni * 16 + (lane & 15);
        const short8 bv = *(const short8*)(Bs + br * 256 + (col ^ ((br & 7) << 3)));
        acc[ni] = __builtin_amdgcn_mfma_f32_16x16x32_bf16(av, bv, acc[ni], 0, 0, 0);
      }
    }
    const int igb = it * 64 + wid * 16 + ((lane >> 4) << 2);
    #pragma unroll
    for (int ni = 0; ni < 4; ++ni) {
      const int jg = jt * 64 + ni * 16 + (lane & 15);
      #pragma unroll
      for (int r2 = 0; r2 < 4; ++r2) {
        const float s = acc[ni][r2] * TEMP_INV;
        rowacc[r2] += ((igb + r2) == jg) ? 0.0f : __expf(s);
      }
    }
  }

  float partial = 0.0f;
  #pragma unroll
  for (int r2 = 0; r2 < 4; ++r2) {
    float v = rowacc[r2];
    v += __shfl_xor(v, 1); v += __shfl_xor(v, 2);
    v += __shfl_xor(v, 4); v += __shfl_xor(v, 8);
    partial += __logf(v);
  }
  partial += __shfl_xor(partial, 16);
  partial += __shfl_xor(partial, 32);

  __shared__ float sn[4];
  if (lane == 0) sn[wid] = partial;
  __syncthreads();
  if (threadIdx.x == 0)
    negp[blockIdx.y * TWO_B + blockIdx.x] = sn[0] + sn[1] + sn[2] + sn[3];
}

__global__ __launch_bounds__(256) void k_fin(
    const float* __restrict__ posp, const float* __restrict__ negp,
    float* __restrict__ out) {
  const int t = threadIdx.x, wid = t >> 6, lane = t & 63;
  const float4 p4 = ((const float4*)posp)[t];
  const float4 n4 = ((const float4*)negp)[t];
  float p = p4.x + p4.y + p4.z + p4.w;
  float n = n4.x + n4.y + n4.z + n4.w;
  #pragma unroll
  for (int m = 1; m < 64; m <<= 1) { p += __shfl_xor(p, m); n += __shfl_xor(n, m); }
  __shared__ float sp[4], sq[4];
  if (lane == 0) { sp[wid] = p; sq[wid] = n; }
  __syncthreads();
  if (t == 0) {
    const float pt = sp[0] + sp[1] + sp[2] + sp[3];
    const float nt = sq[0] + sq[1] + sq[2] + sq[3];
    out[0] = nt * (1.0f / 65536.0f) - pt * (1.0f / 32768.0f);
  }
}

extern "C" void kernel_launch(void* const* d_in, const int* in_sizes, int n_in,
                              void* d_out, int out_size, void* d_ws, size_t ws_size,
                              hipStream_t stream) {
  const float* x  = (const float*)d_in[0];
  const float* xp = (const float*)d_in[1];
  float* wsf = (float*)d_ws;
  float* out = (float*)d_out;

  const size_t need_fast = 4096 + (size_t)65536 * DDIM * 2;   // partials + 32MB zn2
  if (ws_size >= need_fast) {
    float* negp = wsf;                        // 512
    float* posn = wsf + 512;                  // 512
    unsigned short* zn2 = (unsigned short*)(wsf + 1024);
    k_norm_f<<<2048, 256, 0, stream>>>(x, xp, zn2);
    k_neg_f5<<<dim3(TWO_B, 4), 256, 0, stream>>>(zn2, negp, posn);
    k_fin_f<<<1, 256, 0, stream>>>(posn, negp, out);
  } else {
    float* invx = wsf;
    float* invp = wsf + NROWS;
    float* posp = wsf + 2 * NROWS;
    float* negp = wsf + 2 * NROWS + 1024;
    k_norm<<<1024, 256, 0, stream>>>(x, xp, invx, invp, posp);
    k_neg<<<dim3(TWO_B, 8), 256, 0, stream>>>(x, xp, invx, invp, negp);
    k_fin<<<1, 256, 0, stream>>>(posp, negp, out);
  }
}